// Round 6
// baseline (149.450 us; speedup 1.0000x reference)
//
#include <hip/hip_runtime.h>
#include <cstdint>

#define BATCH 4
#define TQ 256
#define TK 256
#define DIM 256
#define HD 256

typedef _Float16 f16x8 __attribute__((ext_vector_type(8)));
typedef float f32x4 __attribute__((ext_vector_type(4)));

union U4H8 { uint4 u; f16x8 v; };

// Opaque def+use: pins a value in a VGPR, prevents sink/remat.
#define KEEP(x) asm volatile("" : "+v"(x))

__device__ __forceinline__ unsigned short f2h(float f) {
    _Float16 h = (_Float16)f;
    unsigned short u;
    __builtin_memcpy(&u, &h, 2);
    return u;
}

__device__ __forceinline__ f16x8 relu8(f16x8 h) {
    f16x8 z = {};
#if __has_builtin(__builtin_elementwise_max)
    return __builtin_elementwise_max(h, z);
#else
#pragma unroll
    for (int i = 0; i < 8; ++i) h[i] = h[i] > (_Float16)0 ? h[i] : (_Float16)0;
    return h;
#endif
}

// prep: blocks 0..255   -> qhh f16 = queries@W1[256:] + b1      [b][q][h]
//       blocks 256..511 -> khh f16 = keys@W1[:256], h-SWIZZLED  [b][k][h ^ ((k&7)<<3)]
//       blocks 512..575 -> W2T[n][c] = (f16)W2[c][n]
__global__ __launch_bounds__(256) void prep_all(
    const float* __restrict__ queries, const float* __restrict__ keys,
    const float* __restrict__ W1, const float* __restrict__ b1,
    const float* __restrict__ W2,
    unsigned short* __restrict__ qhh, unsigned short* __restrict__ khh,
    unsigned short* __restrict__ W2T) {
    int i = blockIdx.x;
    int t = threadIdx.x;
    if (i >= 512) {  // ---- W2 transpose ----
        __shared__ float tile[32][33];
        int bi = i - 512;
        int tx = t & 31, ty = t >> 5;
        int tc = (bi & 7) * 32, tn = (bi >> 3) * 32;
#pragma unroll
        for (int r = 0; r < 4; ++r)
            tile[ty + r * 8][tx] = W2[(tc + ty + r * 8) * HD + tn + tx];
        __syncthreads();
#pragma unroll
        for (int r = 0; r < 4; ++r)
            W2T[(tn + ty + r * 8) * HD + tc + tx] = f2h(tile[tx][ty + r * 8]);
        return;
    }
    bool isQ = i < 256;
    int r0 = (i & 255) * 4;
    const float* X = isQ ? queries : keys;
    const float* W = W1 + (isQ ? DIM * HD : 0);
    __shared__ float xs[4][DIM];
#pragma unroll
    for (int r = 0; r < 4; ++r) xs[r][t] = X[(r0 + r) * DIM + t];
    __syncthreads();
    float acc[4] = {0.f, 0.f, 0.f, 0.f};
#pragma unroll 8
    for (int d = 0; d < DIM; ++d) {
        float w = W[d * HD + t];
#pragma unroll
        for (int r = 0; r < 4; ++r) acc[r] = fmaf(xs[r][d], w, acc[r]);
    }
    if (isQ) {
        float bias = b1[t];
#pragma unroll
        for (int r = 0; r < 4; ++r) qhh[(r0 + r) * HD + t] = f2h(acc[r] + bias);
    } else {
#pragma unroll
        for (int r = 0; r < 4; ++r) {
            int rr = r0 + r;   // swizzle h-position within the row (16B granules)
            khh[rr * HD + (t ^ ((rr & 7) << 3))] = f2h(acc[r]);
        }
    }
}

// One block per (b, q-quad): 512 threads / 8 waves, 1 block/CU, 2 waves/SIMD.
// LDS holds RAW f16 kh chunks (q-independent!), copied by global_load_lds
// (zero staging VALU, loads in flight across the whole chunk). B-fragments
// H=relu(kh+qh) are built in-register at consume time with packed-f16 ops and
// reused across the wave's n-tiles. kh rows are XOR-swizzled (pre-swizzled in
// global by prep) so the per-col fragment read is bank-conflict-free.
// A = W2T slice (n), B = H (k) -> lane-local n-reduction (R5's swap).
__global__ __launch_bounds__(512, 2) void mlp_attn(
    const unsigned short* __restrict__ khh,
    const unsigned short* __restrict__ qhh,
    const unsigned short* __restrict__ W2T,
    const float* __restrict__ b2, const float* __restrict__ W3,
    const float* __restrict__ keys,
    const int* __restrict__ qlens, const int* __restrict__ klens,
    float* __restrict__ out) {
    int orig = blockIdx.x;
    // XCD-chunked swizzle: 256 blocks = 8 XCDs x 32; each XCD sees one batch
    int bid = ((orig & 7) << 5) | (orig >> 3);
    int b = bid >> 6;
    int q0 = (bid & 63) << 2;
    int t = threadIdx.x;
    int qlen = qlens[b];
    float* obase = out + (b * TQ + q0) * DIM;   // 4 rows = 1024 floats
    if (q0 >= qlen) { obase[t] = 0.f; obase[512 + t] = 0.f; return; }
    int klen = klens[b];
    int nch = (klen + 63) >> 6;   // 2..4 chunks of 64 k

    __shared__ unsigned short khbuf[2][64 * HD];  // raw kh chunks, 2x32KB
    __shared__ unsigned short qbuf[4][HD];        // q-quad rows f16, 2KB
    __shared__ float sprt[8][4][TK];              // per-wave score partials, 32KB
    __shared__ float pbuf[4][TK];                 // probs, 4KB
    __shared__ float red[32];

    int w = t >> 6, lane = t & 63;
    int col = lane & 15, quad = lane >> 4;

    // pure-copy staging: 32KB chunk, 4 x global_load_lds(16B) per thread
    auto stage = [&](int c, int d) {
        const char* src = (const char*)(khh + ((size_t)b * TK + (c << 6)) * HD) + t * 16;
        char* dst = (char*)&khbuf[d][0] + t * 16;
#pragma unroll
        for (int i = 0; i < 4; ++i)
            __builtin_amdgcn_global_load_lds((const uint32_t*)(src + i * 8192),
                                             (uint32_t*)(dst + i * 8192), 16, 0, 0);
    };
    stage(0, 0);

    // ---- this wave's W2T slice: n in [w*32, w*32+32) = 16 uint4 = 64 regs ----
    uint4 afr[2][8];
#pragma unroll
    for (int nt = 0; nt < 2; ++nt) {
        int n = (w << 5) + (nt << 4) + col;
        const uint4* r = (const uint4*)(W2T + n * HD) + quad;  // quad -> h-octet
#pragma unroll
        for (int s = 0; s < 8; ++s) afr[nt][s] = r[s * 4];
    }
    // b2/w3 for D rows: n = w*32 + nt*16 + quad*4 + r
    float b2v[2][4], w3v[2][4];
#pragma unroll
    for (int nt = 0; nt < 2; ++nt)
#pragma unroll
        for (int r = 0; r < 4; ++r) {
            int n = (w << 5) + (nt << 4) + (quad << 2) + r;
            b2v[nt][r] = b2[n];
            w3v[nt][r] = W3[n];
        }

    // q-quad rows -> LDS (2KB linear copy)
    if (t < 128)
        *(uint4*)((char*)&qbuf[0][0] + t * 16) =
            *(const uint4*)((const char*)(qhh + ((size_t)b * TQ + q0) * HD) + t * 16);

    // Pin the A slice.
#pragma unroll
    for (int nt = 0; nt < 2; ++nt)
#pragma unroll
        for (int s = 0; s < 8; ++s) {
            KEEP(afr[nt][s].x); KEEP(afr[nt][s].y);
            KEEP(afr[nt][s].z); KEEP(afr[nt][s].w);
        }

    __syncthreads();   // chunk 0 staged (syncthreads drains vmcnt), qbuf ready

    for (int c = 0; c < nch; ++c) {
        int cur = c & 1;
        if (c + 1 < nch) stage(c + 1, cur ^ 1);   // in flight across this chunk
        const unsigned short* kb = &khbuf[cur][0];

#pragma unroll
        for (int q = 0; q < 4; ++q) {
            // 8 qh fragments for this q (broadcast reads), reused across kg
            U4H8 qf[8];
#pragma unroll
            for (int s = 0; s < 8; ++s)
                qf[s].u = *(const uint4*)&qbuf[q][(s << 5) + (quad << 3)];
#pragma unroll
            for (int kg = 0; kg < 4; ++kg) {
                int row = (kg << 4) | col;           // k within chunk
                const unsigned short* kr = kb + row * HD;
                int sw = (row & 7) << 3;
                f32x4 acc0 = {}, acc1 = {};
                __builtin_amdgcn_s_setprio(1);
#pragma unroll
                for (int s = 0; s < 8; ++s) {
                    int el = (((s << 5) | (quad << 3)) ^ sw);
                    U4H8 kf;
                    kf.u = *(const uint4*)(kr + el);
                    f16x8 h = relu8(kf.v + qf[s].v);   // packed f16 add+max
                    U4H8 a0, a1;
                    a0.u = afr[0][s];
                    a1.u = afr[1][s];
                    acc0 = __builtin_amdgcn_mfma_f32_16x16x32_f16(a0.v, h, acc0, 0, 0, 0);
                    acc1 = __builtin_amdgcn_mfma_f32_16x16x32_f16(a1.v, h, acc1, 0, 0, 0);
                }
                __builtin_amdgcn_s_setprio(0);
                // lane-local n-reduce (D: col=k, row=n), 2-stage shfl, 1 write
                float part = 0.f;
#pragma unroll
                for (int r = 0; r < 4; ++r) {
                    part = fmaf(fmaxf(acc0[r] + b2v[0][r], 0.f), w3v[0][r], part);
                    part = fmaf(fmaxf(acc1[r] + b2v[1][r], 0.f), w3v[1][r], part);
                }
                part += __shfl_xor(part, 16, 64);
                part += __shfl_xor(part, 32, 64);
                if (quad == 0)
                    sprt[w][q][(c << 6) | (kg << 4) | col] = part;
            }
        }
        __syncthreads();   // buf cur free; stage(c+1) drained by barrier's vmcnt
    }

    // ---- softmax: group g = t>>8 handles rows 2g, 2g+1; k = t&255 ----
    int g = t >> 8, kk = t & 255, wg = w & 3;
    int r2 = g << 1;
    float sc0 = 0.f, sc1 = 0.f;
#pragma unroll
    for (int wv = 0; wv < 8; ++wv) {
        sc0 += sprt[wv][r2][kk];
        sc1 += sprt[wv][r2 | 1][kk];
    }
    if (kk >= klen) { sc0 = -3.4e38f; sc1 = -3.4e38f; }
    float m0 = sc0, m1 = sc1;
#pragma unroll
    for (int off = 1; off < 64; off <<= 1) {
        m0 = fmaxf(m0, __shfl_xor(m0, off, 64));
        m1 = fmaxf(m1, __shfl_xor(m1, off, 64));
    }
    if (lane == 0) { red[(g << 3) | wg] = m0; red[(g << 3) | 4 | wg] = m1; }
    __syncthreads();
    m0 = fmaxf(fmaxf(red[(g << 3)], red[(g << 3) | 1]),
               fmaxf(red[(g << 3) | 2], red[(g << 3) | 3]));
    m1 = fmaxf(fmaxf(red[(g << 3) | 4], red[(g << 3) | 5]),
               fmaxf(red[(g << 3) | 6], red[(g << 3) | 7]));
    float e0 = (kk < klen) ? __expf(sc0 - m0) : 0.f;
    float e1 = (kk < klen) ? __expf(sc1 - m1) : 0.f;
    float u0 = e0, u1 = e1;
#pragma unroll
    for (int off = 1; off < 64; off <<= 1) {
        u0 += __shfl_xor(u0, off, 64);
        u1 += __shfl_xor(u1, off, 64);
    }
    if (lane == 0) { red[16 | (g << 3) | wg] = u0; red[16 | (g << 3) | 4 | wg] = u1; }
    __syncthreads();
    float d0 = (red[16 | (g << 3)] + red[16 | (g << 3) | 1]) +
               (red[16 | (g << 3) | 2] + red[16 | (g << 3) | 3]);
    float d1 = (red[16 | (g << 3) | 4] + red[16 | (g << 3) | 5]) +
               (red[16 | (g << 3) | 6] + red[16 | (g << 3) | 7]);
    pbuf[r2][kk] = e0 / d0;
    pbuf[r2 | 1][kk] = e1 / d1;
    __syncthreads();

    // ---- PV: group g computes rows 2g,2g+1 sharing each keys load ----
    const float* kp = keys + b * TK * DIM + kk;   // kk = channel, coalesced
    float a0 = 0.f, a1 = 0.f;
#pragma unroll 8
    for (int k = 0; k < klen; ++k) {
        float v = kp[k * DIM];
        a0 = fmaf(pbuf[r2][k], v, a0);
        a1 = fmaf(pbuf[r2 | 1][k], v, a1);
    }
    float* orow = obase + r2 * DIM;
    orow[kk] = (q0 + r2 < qlen) ? a0 : 0.f;
    orow[DIM + kk] = (q0 + r2 + 1 < qlen) ? a1 : 0.f;
}

extern "C" void kernel_launch(void* const* d_in, const int* in_sizes, int n_in,
                              void* d_out, int out_size, void* d_ws, size_t ws_size,
                              hipStream_t stream) {
    (void)in_sizes; (void)n_in; (void)out_size; (void)ws_size;
    const float* queries = (const float*)d_in[0];
    const float* keys    = (const float*)d_in[1];
    const int*   qlens   = (const int*)d_in[2];
    const int*   klens   = (const int*)d_in[3];
    const float* W1      = (const float*)d_in[4];
    const float* b1      = (const float*)d_in[5];
    const float* W2      = (const float*)d_in[6];
    const float* b2      = (const float*)d_in[7];
    const float* W3      = (const float*)d_in[8];
    float* out = (float*)d_out;

    unsigned short* qhh = (unsigned short*)d_ws;          // 512 KB f16
    unsigned short* khh = qhh + BATCH * TQ * HD;          // 512 KB f16 (swizzled)
    unsigned short* W2T = khh + BATCH * TK * HD;          // 128 KB f16

    prep_all<<<576, 256, 0, stream>>>(queries, keys, W1, b1, W2, qhh, khh, W2T);
    mlp_attn<<<256, 512, 0, stream>>>(
        khh, qhh, W2T, b2, W3, keys, qlens, klens, out);
}